// Round 9
// baseline (721.800 us; speedup 1.0000x reference)
//
#include <hip/hip_runtime.h>
#include <hip/hip_bf16.h>

// FourierBlock: B=16, L=4096, H=3, E=512, M=128 modes.
// Pipeline:
//   1. build_ta: T_A[m2=256][l=4096] bf16  (cos / -sin interleaved)
//   2. build_tc: T_C[l=4096][m2=256] bf16  (irfft scale c_m/L folded in HERE ONLY)
//   3. gemm_a  : Xbf[h,b,i,m2] bf16 = q[b,:,ch] . T_A^T  (fused f32 load +
//                transpose + cast + MFMA, K=4096; q read exactly once)
//   4. stage_b : complex channel mix, K-SPLIT over i (ic=0 -> Ybf, ic=1 -> P1);
//                r6-proven 2-i/12-load bodies, 6 waves/SIMD
//   5. reduce_y: Ybf += P1 (bf16 halves summed in f32)
//   6. gemm<1> : out[(b,h,o)][l] f32 = Ybf . T_C^T        (MFMA bf16, K=256)
//
// ws: Xbf bf16 12,582,912 B @0 | P1 bf16 12,582,912 B @12582912
//     Ybf bf16 12,582,912 B @25165824 | T_A 2 MB @37748736 | T_C 2 MB @39845888

#define L_TOT 4096

typedef __attribute__((ext_vector_type(4))) float f32x4;
typedef __attribute__((ext_vector_type(4))) unsigned u32x4;
typedef __attribute__((ext_vector_type(8))) short s16x8;
typedef __attribute__((ext_vector_type(4))) unsigned short u16x4;

__device__ __forceinline__ unsigned short f2bf(float f) {
    unsigned u = __builtin_bit_cast(unsigned, f);
    u = (u + 0x7fffu + ((u >> 16) & 1u)) >> 16;
    return (unsigned short)u;
}

__device__ __forceinline__ void gload_lds16(const void* g, void* l) {
    __builtin_amdgcn_global_load_lds((const __attribute__((address_space(1))) void*)g,
                                     (__attribute__((address_space(3))) void*)l,
                                     16, 0, 0);
}

__global__ __launch_bounds__(256) void build_ta(const int* __restrict__ index,
                                                unsigned short* __restrict__ T_A) {
    const int idx = blockIdx.x * 256 + threadIdx.x;
    const int m2 = idx >> 12;
    const int l  = idx & (L_TOT - 1);
    const int k  = index[m2 >> 1];
    const int tt = (k * l) & (L_TOT - 1);
    const float x = (float)tt * (1.0f / 2048.0f);
    T_A[idx] = f2bf((m2 & 1) ? -sinpif(x) : cospif(x));
}

__global__ __launch_bounds__(256) void build_tc(const int* __restrict__ index,
                                                unsigned short* __restrict__ T_C) {
    const int idx = blockIdx.x * 256 + threadIdx.x;
    const int l  = idx >> 8;
    const int m2 = idx & 255;
    const int k  = index[m2 >> 1];
    const int tt = (k * l) & (L_TOT - 1);
    const float x = (float)tt * (1.0f / 2048.0f);
    const float s = (k == 0 ? 1.0f : 2.0f) * (1.0f / (float)L_TOT);
    T_C[idx] = f2bf(s * ((m2 & 1) ? -sinpif(x) : cospif(x)));
}

// ---- gemm_a: fused transpose+cast+GEMM (stage A of the DFT) ----
// grid 384 = b(16) x cht(24); block 256 = 4 waves.
__global__ __launch_bounds__(256) void gemm_a(const float* __restrict__ q,
                                              const unsigned short* __restrict__ T_A,
                                              unsigned short* __restrict__ Xbf) {
    __shared__ unsigned short As[64 * 64];    // [ch][l^swz]  8 KB
    __shared__ unsigned short Bs[256 * 64];   // [m2][l^swz] 32 KB

    const int bid = blockIdx.x;
    const int b   = bid / 24;
    const int cht = bid % 24;
    const int ch0 = cht * 64;
    const int h   = ch0 >> 9;
    const int i0  = ch0 & 511;
    const int t   = threadIdx.x;
    const int lane = t & 63;
    const int w    = t >> 6;
    const int chq  = t & 15;
    const int lg   = t >> 4;

    const float* qb = q + (size_t)b * L_TOT * 1536 + ch0 + chq * 4;

    f32x4 acc[4][4];
#pragma unroll
    for (int mi = 0; mi < 4; ++mi)
#pragma unroll
        for (int ni = 0; ni < 4; ++ni) acc[mi][ni] = (f32x4)0.0f;

    for (int kt = 0; kt < L_TOT; kt += 64) {
        __syncthreads();
#pragma unroll
        for (int p = 0; p < 8; ++p) {
            const int u = p * 256 + t;
            const int row = u >> 3, c16 = u & 7;
            const unsigned short* src = T_A + (size_t)row * L_TOT + kt + ((c16 ^ (row & 7)) * 8);
            unsigned short* dst = Bs + (size_t)(p * 256 + w * 64) * 8;
            gload_lds16(src, dst);
        }
        f32x4 v[4];
#pragma unroll
        for (int r = 0; r < 4; ++r)
            v[r] = *reinterpret_cast<const f32x4*>(qb + (size_t)(kt + lg * 4 + r) * 1536);
#pragma unroll
        for (int j = 0; j < 4; ++j) {
            const int c = chq * 4 + j;
            uint2 pk;
            pk.x = f2bf(v[0][j]) | ((unsigned)f2bf(v[1][j]) << 16);
            pk.y = f2bf(v[2][j]) | ((unsigned)f2bf(v[3][j]) << 16);
            *reinterpret_cast<uint2*>(As + c * 64 + ((lg * 4) ^ ((c & 7) << 3))) = pk;
        }
        __syncthreads();

#pragma unroll
        for (int kk = 0; kk < 2; ++kk) {
            const int c16 = kk * 4 + (lane >> 4);
            s16x8 af[4], bfr[4];
#pragma unroll
            for (int mi = 0; mi < 4; ++mi) {
                const int row = mi * 16 + (lane & 15);
                af[mi] = *reinterpret_cast<const s16x8*>(As + row * 64 + ((c16 ^ (row & 7)) * 8));
            }
#pragma unroll
            for (int ni = 0; ni < 4; ++ni) {
                const int row = w * 64 + ni * 16 + (lane & 15);
                bfr[ni] = *reinterpret_cast<const s16x8*>(Bs + row * 64 + ((c16 ^ (row & 7)) * 8));
            }
#pragma unroll
            for (int mi = 0; mi < 4; ++mi)
#pragma unroll
                for (int ni = 0; ni < 4; ++ni)
                    acc[mi][ni] = __builtin_amdgcn_mfma_f32_16x16x32_bf16(af[mi], bfr[ni], acc[mi][ni], 0, 0, 0);
        }
    }

    const size_t cbase = (((size_t)h * 16 + b) * 512 + i0) * 256;
#pragma unroll
    for (int mi = 0; mi < 4; ++mi) {
        const int r0 = mi * 16 + (lane >> 4) * 4;
#pragma unroll
        for (int ni = 0; ni < 4; ++ni) {
            const int col = w * 64 + ni * 16 + (lane & 15);
#pragma unroll
            for (int j = 0; j < 4; ++j)
                Xbf[cbase + (size_t)(r0 + j) * 256 + col] = f2bf(acc[mi][ni][j]);
        }
    }
}

// ---- MFMA GEMM (stage C): out[(b,h,o)][l] f32 = Ybf . T_C^T ----
template <int MODE>
__global__ __launch_bounds__(256) void gemm_bf16(const unsigned short* __restrict__ A,
                                                 const unsigned short* __restrict__ Bt,
                                                 void* __restrict__ Cv) {
    constexpr int BM   = 128;
    constexpr int BK   = 64;
    constexpr int KTOT = 256;
    constexpr int LDAB = 256;
    constexpr int LDC  = 4096;
    constexpr int MFR  = BM / 32;
    constexpr int APASS = BM * 8 / 256;
    constexpr int BPASS = 4;

    __shared__ unsigned short As[BM * BK];
    __shared__ unsigned short Bs[128 * BK];

    const int t = threadIdx.x;
    const int lane = t & 63;
    const int w = t >> 6;
    const int wr = w >> 1, wc = w & 1;

    const int mt = blockIdx.x >> 5, nt = blockIdx.x & 31;
    const unsigned short* Ab = A + (size_t)mt * 128 * 256;
    const unsigned short* Bb = Bt + (size_t)nt * 128 * 256;
    const size_t cbase = (size_t)mt * 128 * 4096 + nt * 128;

    f32x4 acc[MFR][4];
#pragma unroll
    for (int mi = 0; mi < MFR; ++mi)
#pragma unroll
        for (int ni = 0; ni < 4; ++ni) acc[mi][ni] = (f32x4)0.0f;

    for (int kt = 0; kt < KTOT; kt += BK) {
        __syncthreads();
#pragma unroll
        for (int p = 0; p < APASS; ++p) {
            const int u = p * 256 + t;
            const int row = u >> 3, c16 = u & 7;
            const unsigned short* src = Ab + (size_t)row * LDAB + kt + ((c16 ^ (row & 7)) * 8);
            unsigned short* dst = As + (size_t)(p * 256 + w * 64) * 8;
            gload_lds16(src, dst);
        }
#pragma unroll
        for (int p = 0; p < BPASS; ++p) {
            const int u = p * 256 + t;
            const int row = u >> 3, c16 = u & 7;
            const unsigned short* src = Bb + (size_t)row * LDAB + kt + ((c16 ^ (row & 7)) * 8);
            unsigned short* dst = Bs + (size_t)(p * 256 + w * 64) * 8;
            gload_lds16(src, dst);
        }
        __syncthreads();

#pragma unroll
        for (int kk = 0; kk < 2; ++kk) {
            const int c16 = kk * 4 + (lane >> 4);
            s16x8 af[MFR], bfr[4];
#pragma unroll
            for (int mi = 0; mi < MFR; ++mi) {
                const int row = wr * (BM / 2) + mi * 16 + (lane & 15);
                af[mi] = *reinterpret_cast<const s16x8*>(As + row * BK + ((c16 ^ (row & 7)) * 8));
            }
#pragma unroll
            for (int ni = 0; ni < 4; ++ni) {
                const int row = wc * 64 + ni * 16 + (lane & 15);
                bfr[ni] = *reinterpret_cast<const s16x8*>(Bs + row * BK + ((c16 ^ (row & 7)) * 8));
            }
#pragma unroll
            for (int mi = 0; mi < MFR; ++mi)
#pragma unroll
                for (int ni = 0; ni < 4; ++ni)
                    acc[mi][ni] = __builtin_amdgcn_mfma_f32_16x16x32_bf16(af[mi], bfr[ni], acc[mi][ni], 0, 0, 0);
        }
    }

#pragma unroll
    for (int mi = 0; mi < MFR; ++mi) {
        const int r0 = wr * (BM / 2) + mi * 16 + (lane >> 4) * 4;
#pragma unroll
        for (int ni = 0; ni < 4; ++ni) {
            const int col = wc * 64 + ni * 16 + (lane & 15);
#pragma unroll
            for (int j = 0; j < 4; ++j)
                ((float*)Cv)[cbase + (size_t)(r0 + j) * LDC + col] = acc[mi][ni][j];
        }
    }
}

// ---- Stage B v6: r6 body, K-split over i, 6 waves/SIMD ----
// grid 1536; bid = 64*(g/8) + 8*sub + (g%8), g = h*64+ot in [0,192),
// sub = ic*4+bq in [0,8)  -> the 8 blocks sharing a W slice land on one XCD.
// wave w: o = ot*8 + w*2 + {0,1}; lane: m4 = lane&31, h1 = lane>>5;
// b = bq*4 + h1*2 + {0,1}.  Per 2-i body: 8 W float4 (HBM) + 4 X uint4 (L2),
// one drain, 128 FMA.  ic selects i-half and output buffer (Ybf / P1).
__global__ __launch_bounds__(256, 6) void stage_b(const unsigned short* __restrict__ Xbf,
                                                  const float* __restrict__ wr,
                                                  const float* __restrict__ wi,
                                                  unsigned short* __restrict__ Y0,
                                                  unsigned short* __restrict__ P1) {
    const int bid = blockIdx.x;
    const int gq  = bid >> 6;            // 0..23
    const int sub = (bid >> 3) & 7;      // ic*4 + bq
    const int gr  = bid & 7;
    const int g   = gq * 8 + gr;         // h*64 + ot
    const int h   = g >> 6;
    const int ot  = g & 63;
    const int ic  = sub >> 2;
    const int bq  = sub & 3;
    const int t    = threadIdx.x;
    const int lane = t & 63;
    const int w    = t >> 6;
    const int m4   = lane & 31;
    const int h1   = lane >> 5;
    const int b0   = bq * 4 + h1 * 2;          // b0, b0+1
    const int o    = ot * 8 + w * 2;           // o, o+1
    const int i_lo = ic * 256;

    const size_t wbase = (size_t)h * 33554432 + (size_t)o * 128 + m4 * 4;
    const float* wrp = wr + wbase;             // + i*65536; o+1 -> +128
    const float* wip = wi + wbase;
    const unsigned short* x0 = Xbf + (size_t)(h * 16 + b0) * 512 * 256 + m4 * 8;  // + i*256; b+1 -> +131072

    float aR[2][2][4], aI[2][2][4];            // [b][o][m]
#pragma unroll
    for (int bb = 0; bb < 2; ++bb)
#pragma unroll
        for (int oo = 0; oo < 2; ++oo)
#pragma unroll
            for (int j = 0; j < 4; ++j) { aR[bb][oo][j] = 0.f; aI[bb][oo][j] = 0.f; }

#pragma unroll 1
    for (int i = i_lo; i < i_lo + 256; i += 2) {
        f32x4 wrv[2][2], wiv[2][2];            // [istep][o]
        u32x4 xv[2][2];                        // [istep][b]
#pragma unroll
        for (int s = 0; s < 2; ++s) {
            const size_t io = (size_t)(i + s) * 65536;
            wrv[s][0] = *reinterpret_cast<const f32x4*>(wrp + io);
            wrv[s][1] = *reinterpret_cast<const f32x4*>(wrp + io + 128);
            wiv[s][0] = *reinterpret_cast<const f32x4*>(wip + io);
            wiv[s][1] = *reinterpret_cast<const f32x4*>(wip + io + 128);
        }
#pragma unroll
        for (int s = 0; s < 2; ++s) {
            const size_t xo = (size_t)(i + s) * 256;
            xv[s][0] = *reinterpret_cast<const u32x4*>(x0 + xo);
            xv[s][1] = *reinterpret_cast<const u32x4*>(x0 + 131072 + xo);
        }
#pragma unroll
        for (int s = 0; s < 2; ++s)
#pragma unroll
            for (int bb = 0; bb < 2; ++bb) {
#pragma unroll
                for (int j = 0; j < 4; ++j) {
                    const unsigned xu = xv[s][bb][j];
                    const float xr = __builtin_bit_cast(float, xu << 16);
                    const float xi = __builtin_bit_cast(float, xu & 0xffff0000u);
#pragma unroll
                    for (int oo = 0; oo < 2; ++oo) {
                        const float wrj = wrv[s][oo][j];
                        const float wij = wiv[s][oo][j];
                        aR[bb][oo][j] = fmaf(xr, wrj, aR[bb][oo][j]);
                        aR[bb][oo][j] = fmaf(-xi, wij, aR[bb][oo][j]);
                        aI[bb][oo][j] = fmaf(xr, wij, aI[bb][oo][j]);
                        aI[bb][oo][j] = fmaf(xi, wrj, aI[bb][oo][j]);
                    }
                }
            }
    }

    unsigned short* yout = ic ? P1 : Y0;
#pragma unroll
    for (int bb = 0; bb < 2; ++bb)
#pragma unroll
        for (int oo = 0; oo < 2; ++oo) {
            const size_t row = ((size_t)(b0 + bb) * 3 + h) * 512 + o + oo;
            uint4 pk;
            pk.x = f2bf(aR[bb][oo][0]) | ((unsigned)f2bf(aI[bb][oo][0]) << 16);
            pk.y = f2bf(aR[bb][oo][1]) | ((unsigned)f2bf(aI[bb][oo][1]) << 16);
            pk.z = f2bf(aR[bb][oo][2]) | ((unsigned)f2bf(aI[bb][oo][2]) << 16);
            pk.w = f2bf(aR[bb][oo][3]) | ((unsigned)f2bf(aI[bb][oo][3]) << 16);
            *reinterpret_cast<uint4*>(reinterpret_cast<char*>(yout) + row * 512 + m4 * 16) = pk;
        }
}

// ---- reduce_y: Ybf += P1 (bf16 pairs, f32 add) ----
__global__ __launch_bounds__(256) void reduce_y(unsigned short* __restrict__ Ybf,
                                                const unsigned short* __restrict__ P1) {
    const int idx = blockIdx.x * 256 + threadIdx.x;   // uint4 index, 786432 total
    const uint4 a = reinterpret_cast<const uint4*>(Ybf)[idx];
    const uint4 b = reinterpret_cast<const uint4*>(P1)[idx];
    const unsigned av[4] = {a.x, a.y, a.z, a.w};
    const unsigned bv[4] = {b.x, b.y, b.z, b.w};
    unsigned rv[4];
#pragma unroll
    for (int j = 0; j < 4; ++j) {
        const float xr = __builtin_bit_cast(float, av[j] << 16);
        const float xi = __builtin_bit_cast(float, av[j] & 0xffff0000u);
        const float yr = __builtin_bit_cast(float, bv[j] << 16);
        const float yi = __builtin_bit_cast(float, bv[j] & 0xffff0000u);
        rv[j] = f2bf(xr + yr) | ((unsigned)f2bf(xi + yi) << 16);
    }
    uint4 r;
    r.x = rv[0]; r.y = rv[1]; r.z = rv[2]; r.w = rv[3];
    reinterpret_cast<uint4*>(Ybf)[idx] = r;
}

extern "C" void kernel_launch(void* const* d_in, const int* in_sizes, int n_in,
                              void* d_out, int out_size, void* d_ws, size_t ws_size,
                              hipStream_t stream) {
    const float* q     = (const float*)d_in[0];
    const float* w_re  = (const float*)d_in[1];
    const float* w_im  = (const float*)d_in[2];
    const int*   index = (const int*)d_in[3];

    char* ws = (char*)d_ws;
    unsigned short* Xbf = (unsigned short*)(ws);                // 12,582,912 B
    unsigned short* P1  = (unsigned short*)(ws + 12582912);     // 12,582,912 B
    unsigned short* Ybf = (unsigned short*)(ws + 25165824);     // 12,582,912 B
    unsigned short* T_A = (unsigned short*)(ws + 37748736);
    unsigned short* T_C = (unsigned short*)(ws + 39845888);

    build_ta<<<4096, 256, 0, stream>>>(index, T_A);
    build_tc<<<4096, 256, 0, stream>>>(index, T_C);
    gemm_a<<<384, 256, 0, stream>>>(q, T_A, Xbf);
    stage_b<<<1536, 256, 0, stream>>>(Xbf, w_re, w_im, Ybf, P1);
    reduce_y<<<3072, 256, 0, stream>>>(Ybf, P1);
    gemm_bf16<1><<<6144, 256, 0, stream>>>(Ybf, T_C, (void*)d_out);
}

// Round 10
// 639.450 us; speedup vs baseline: 1.1288x; 1.1288x over previous
//
#include <hip/hip_runtime.h>
#include <hip/hip_bf16.h>

// FourierBlock: B=16, L=4096, H=3, E=512, M=128 modes.
// Pipeline:
//   1. build_ta: T_A[m2=256][l=4096] bf16  (cos / -sin interleaved)
//   2. build_tc: T_C[l=4096][m2=256] bf16  (irfft scale c_m/L folded in HERE ONLY)
//   3. gemm_a  : Xbf[h,b,i,m2] bf16 = q[b,:,ch] . T_A^T  (fused f32 load +
//                transpose + cast + MFMA, K=4096; q read exactly once)
//   4. stage_b : Ybf[(b,h,o)][m2] bf16 = complex channel mix
//                (v7: 4b x 4o x 2m thread tile -> halves W and X cache re-reads;
//                1-i bodies with 12 coalesced loads, no LDS, no barriers)
//   5. gemm<1> : out[(b,h,o)][l] f32 = Ybf . T_C^T        (MFMA bf16, K=256)
//
// ws: Xbf bf16 12,582,912 B @0 | (12.6 MB unused) | Ybf bf16 12,582,912 B @25165824
//     T_A 2 MB @37748736 | T_C 2 MB @39845888

#define L_TOT 4096

typedef __attribute__((ext_vector_type(4))) float f32x4;
typedef __attribute__((ext_vector_type(2))) float f32x2;
typedef __attribute__((ext_vector_type(2))) unsigned u32x2;
typedef __attribute__((ext_vector_type(8))) short s16x8;
typedef __attribute__((ext_vector_type(4))) unsigned short u16x4;

__device__ __forceinline__ unsigned short f2bf(float f) {
    unsigned u = __builtin_bit_cast(unsigned, f);
    u = (u + 0x7fffu + ((u >> 16) & 1u)) >> 16;
    return (unsigned short)u;
}

__device__ __forceinline__ void gload_lds16(const void* g, void* l) {
    __builtin_amdgcn_global_load_lds((const __attribute__((address_space(1))) void*)g,
                                     (__attribute__((address_space(3))) void*)l,
                                     16, 0, 0);
}

__global__ __launch_bounds__(256) void build_ta(const int* __restrict__ index,
                                                unsigned short* __restrict__ T_A) {
    const int idx = blockIdx.x * 256 + threadIdx.x;
    const int m2 = idx >> 12;
    const int l  = idx & (L_TOT - 1);
    const int k  = index[m2 >> 1];
    const int tt = (k * l) & (L_TOT - 1);
    const float x = (float)tt * (1.0f / 2048.0f);
    T_A[idx] = f2bf((m2 & 1) ? -sinpif(x) : cospif(x));
}

__global__ __launch_bounds__(256) void build_tc(const int* __restrict__ index,
                                                unsigned short* __restrict__ T_C) {
    const int idx = blockIdx.x * 256 + threadIdx.x;
    const int l  = idx >> 8;
    const int m2 = idx & 255;
    const int k  = index[m2 >> 1];
    const int tt = (k * l) & (L_TOT - 1);
    const float x = (float)tt * (1.0f / 2048.0f);
    const float s = (k == 0 ? 1.0f : 2.0f) * (1.0f / (float)L_TOT);
    T_C[idx] = f2bf(s * ((m2 & 1) ? -sinpif(x) : cospif(x)));
}

// ---- gemm_a: fused transpose+cast+GEMM (stage A of the DFT) ----
// grid 384 = b(16) x cht(24); block 256 = 4 waves.
__global__ __launch_bounds__(256) void gemm_a(const float* __restrict__ q,
                                              const unsigned short* __restrict__ T_A,
                                              unsigned short* __restrict__ Xbf) {
    __shared__ unsigned short As[64 * 64];    // [ch][l^swz]  8 KB
    __shared__ unsigned short Bs[256 * 64];   // [m2][l^swz] 32 KB

    const int bid = blockIdx.x;
    const int b   = bid / 24;
    const int cht = bid % 24;
    const int ch0 = cht * 64;
    const int h   = ch0 >> 9;
    const int i0  = ch0 & 511;
    const int t   = threadIdx.x;
    const int lane = t & 63;
    const int w    = t >> 6;
    const int chq  = t & 15;
    const int lg   = t >> 4;

    const float* qb = q + (size_t)b * L_TOT * 1536 + ch0 + chq * 4;

    f32x4 acc[4][4];
#pragma unroll
    for (int mi = 0; mi < 4; ++mi)
#pragma unroll
        for (int ni = 0; ni < 4; ++ni) acc[mi][ni] = (f32x4)0.0f;

    for (int kt = 0; kt < L_TOT; kt += 64) {
        __syncthreads();
#pragma unroll
        for (int p = 0; p < 8; ++p) {
            const int u = p * 256 + t;
            const int row = u >> 3, c16 = u & 7;
            const unsigned short* src = T_A + (size_t)row * L_TOT + kt + ((c16 ^ (row & 7)) * 8);
            unsigned short* dst = Bs + (size_t)(p * 256 + w * 64) * 8;
            gload_lds16(src, dst);
        }
        f32x4 v[4];
#pragma unroll
        for (int r = 0; r < 4; ++r)
            v[r] = *reinterpret_cast<const f32x4*>(qb + (size_t)(kt + lg * 4 + r) * 1536);
#pragma unroll
        for (int j = 0; j < 4; ++j) {
            const int c = chq * 4 + j;
            uint2 pk;
            pk.x = f2bf(v[0][j]) | ((unsigned)f2bf(v[1][j]) << 16);
            pk.y = f2bf(v[2][j]) | ((unsigned)f2bf(v[3][j]) << 16);
            *reinterpret_cast<uint2*>(As + c * 64 + ((lg * 4) ^ ((c & 7) << 3))) = pk;
        }
        __syncthreads();

#pragma unroll
        for (int kk = 0; kk < 2; ++kk) {
            const int c16 = kk * 4 + (lane >> 4);
            s16x8 af[4], bfr[4];
#pragma unroll
            for (int mi = 0; mi < 4; ++mi) {
                const int row = mi * 16 + (lane & 15);
                af[mi] = *reinterpret_cast<const s16x8*>(As + row * 64 + ((c16 ^ (row & 7)) * 8));
            }
#pragma unroll
            for (int ni = 0; ni < 4; ++ni) {
                const int row = w * 64 + ni * 16 + (lane & 15);
                bfr[ni] = *reinterpret_cast<const s16x8*>(Bs + row * 64 + ((c16 ^ (row & 7)) * 8));
            }
#pragma unroll
            for (int mi = 0; mi < 4; ++mi)
#pragma unroll
                for (int ni = 0; ni < 4; ++ni)
                    acc[mi][ni] = __builtin_amdgcn_mfma_f32_16x16x32_bf16(af[mi], bfr[ni], acc[mi][ni], 0, 0, 0);
        }
    }

    const size_t cbase = (((size_t)h * 16 + b) * 512 + i0) * 256;
#pragma unroll
    for (int mi = 0; mi < 4; ++mi) {
        const int r0 = mi * 16 + (lane >> 4) * 4;
#pragma unroll
        for (int ni = 0; ni < 4; ++ni) {
            const int col = w * 64 + ni * 16 + (lane & 15);
#pragma unroll
            for (int j = 0; j < 4; ++j)
                Xbf[cbase + (size_t)(r0 + j) * 256 + col] = f2bf(acc[mi][ni][j]);
        }
    }
}

// ---- MFMA GEMM (stage C): out[(b,h,o)][l] f32 = Ybf . T_C^T ----
template <int MODE>
__global__ __launch_bounds__(256) void gemm_bf16(const unsigned short* __restrict__ A,
                                                 const unsigned short* __restrict__ Bt,
                                                 void* __restrict__ Cv) {
    constexpr int BM   = 128;
    constexpr int BK   = 64;
    constexpr int KTOT = 256;
    constexpr int LDAB = 256;
    constexpr int LDC  = 4096;
    constexpr int MFR  = BM / 32;
    constexpr int APASS = BM * 8 / 256;
    constexpr int BPASS = 4;

    __shared__ unsigned short As[BM * BK];
    __shared__ unsigned short Bs[128 * BK];

    const int t = threadIdx.x;
    const int lane = t & 63;
    const int w = t >> 6;
    const int wr = w >> 1, wc = w & 1;

    const int mt = blockIdx.x >> 5, nt = blockIdx.x & 31;
    const unsigned short* Ab = A + (size_t)mt * 128 * 256;
    const unsigned short* Bb = Bt + (size_t)nt * 128 * 256;
    const size_t cbase = (size_t)mt * 128 * 4096 + nt * 128;

    f32x4 acc[MFR][4];
#pragma unroll
    for (int mi = 0; mi < MFR; ++mi)
#pragma unroll
        for (int ni = 0; ni < 4; ++ni) acc[mi][ni] = (f32x4)0.0f;

    for (int kt = 0; kt < KTOT; kt += BK) {
        __syncthreads();
#pragma unroll
        for (int p = 0; p < APASS; ++p) {
            const int u = p * 256 + t;
            const int row = u >> 3, c16 = u & 7;
            const unsigned short* src = Ab + (size_t)row * LDAB + kt + ((c16 ^ (row & 7)) * 8);
            unsigned short* dst = As + (size_t)(p * 256 + w * 64) * 8;
            gload_lds16(src, dst);
        }
#pragma unroll
        for (int p = 0; p < BPASS; ++p) {
            const int u = p * 256 + t;
            const int row = u >> 3, c16 = u & 7;
            const unsigned short* src = Bb + (size_t)row * LDAB + kt + ((c16 ^ (row & 7)) * 8);
            unsigned short* dst = Bs + (size_t)(p * 256 + w * 64) * 8;
            gload_lds16(src, dst);
        }
        __syncthreads();

#pragma unroll
        for (int kk = 0; kk < 2; ++kk) {
            const int c16 = kk * 4 + (lane >> 4);
            s16x8 af[MFR], bfr[4];
#pragma unroll
            for (int mi = 0; mi < MFR; ++mi) {
                const int row = wr * (BM / 2) + mi * 16 + (lane & 15);
                af[mi] = *reinterpret_cast<const s16x8*>(As + row * BK + ((c16 ^ (row & 7)) * 8));
            }
#pragma unroll
            for (int ni = 0; ni < 4; ++ni) {
                const int row = wc * 64 + ni * 16 + (lane & 15);
                bfr[ni] = *reinterpret_cast<const s16x8*>(Bs + row * BK + ((c16 ^ (row & 7)) * 8));
            }
#pragma unroll
            for (int mi = 0; mi < MFR; ++mi)
#pragma unroll
                for (int ni = 0; ni < 4; ++ni)
                    acc[mi][ni] = __builtin_amdgcn_mfma_f32_16x16x32_bf16(af[mi], bfr[ni], acc[mi][ni], 0, 0, 0);
        }
    }

#pragma unroll
    for (int mi = 0; mi < MFR; ++mi) {
        const int r0 = wr * (BM / 2) + mi * 16 + (lane >> 4) * 4;
#pragma unroll
        for (int ni = 0; ni < 4; ++ni) {
            const int col = wc * 64 + ni * 16 + (lane & 15);
#pragma unroll
            for (int j = 0; j < 4; ++j)
                ((float*)Cv)[cbase + (size_t)(r0 + j) * LDC + col] = acc[mi][ni][j];
        }
    }
}

// ---- Stage B v7: 4b x 4o x 2m thread tile, halved cache re-reads ----
// grid 768: bid = bq*384 + h*128 + ot  (bq siblings = same XCD, 384%8==0)
// block 128 = 2 waves; wave w: b0 = bq*8 + w*4 (thread covers b0..b0+3)
// block covers o0 = ot*4 .. +3 (thread covers all 4 o)
// lane: m-pair index = lane (m = lane*2, lane*2+1)
// Per 1-i body: 8 W f32x2 + 4 X u32x2 (all 512 B/wave coalesced), 128 FMA.
// W re-read x2 (1.6 GB), X re-read x128 (1.6 GB) -- half of r6's 6.4 GB.
__global__ __launch_bounds__(128, 3) void stage_b(const unsigned short* __restrict__ Xbf,
                                                  const float* __restrict__ wr,
                                                  const float* __restrict__ wi,
                                                  unsigned short* __restrict__ Ybf) {
    const int bid = blockIdx.x;
    const int bq  = bid / 384;
    const int g   = bid % 384;           // h*128 + ot
    const int h   = g >> 7;
    const int ot  = g & 127;
    const int t    = threadIdx.x;
    const int lane = t & 63;
    const int w    = t >> 6;
    const int b0   = bq * 8 + w * 4;     // b0..b0+3
    const int o0   = ot * 4;             // o0..o0+3

    const size_t wbase = (size_t)h * 33554432 + (size_t)o0 * 128 + lane * 2;
    const float* wrp = wr + wbase;       // + i*65536; o+1 -> +128
    const float* wip = wi + wbase;
    // Xbf[h][b][i][m2]: base at (h,b0), + bb*131072 + i*256 + lane*4
    const unsigned short* x0 = Xbf + (size_t)(h * 16 + b0) * 512 * 256 + lane * 4;

    float aR[4][4][2], aI[4][4][2];      // [b][o][m]
#pragma unroll
    for (int bb = 0; bb < 4; ++bb)
#pragma unroll
        for (int oo = 0; oo < 4; ++oo) {
            aR[bb][oo][0] = aR[bb][oo][1] = 0.f;
            aI[bb][oo][0] = aI[bb][oo][1] = 0.f;
        }

#pragma unroll 1
    for (int i = 0; i < 512; ++i) {
        // issue all 12 loads first
        f32x2 wrv[4], wiv[4];
        u32x2 xv[4];
        const size_t io = (size_t)i * 65536;
#pragma unroll
        for (int oo = 0; oo < 4; ++oo) {
            wrv[oo] = *reinterpret_cast<const f32x2*>(wrp + io + oo * 128);
            wiv[oo] = *reinterpret_cast<const f32x2*>(wip + io + oo * 128);
        }
        const size_t xo = (size_t)i * 256;
#pragma unroll
        for (int bb = 0; bb < 4; ++bb)
            xv[bb] = *reinterpret_cast<const u32x2*>(x0 + (size_t)bb * 131072 + xo);

#pragma unroll
        for (int bb = 0; bb < 4; ++bb) {
            float xr[2], xi[2];
#pragma unroll
            for (int mm = 0; mm < 2; ++mm) {
                const unsigned xu = xv[bb][mm];
                xr[mm] = __builtin_bit_cast(float, xu << 16);
                xi[mm] = __builtin_bit_cast(float, xu & 0xffff0000u);
            }
#pragma unroll
            for (int oo = 0; oo < 4; ++oo)
#pragma unroll
                for (int mm = 0; mm < 2; ++mm) {
                    const float wrj = wrv[oo][mm];
                    const float wij = wiv[oo][mm];
                    aR[bb][oo][mm] = fmaf(xr[mm], wrj, aR[bb][oo][mm]);
                    aR[bb][oo][mm] = fmaf(-xi[mm], wij, aR[bb][oo][mm]);
                    aI[bb][oo][mm] = fmaf(xr[mm], wij, aI[bb][oo][mm]);
                    aI[bb][oo][mm] = fmaf(xi[mm], wrj, aI[bb][oo][mm]);
                }
        }
    }

    // Ybf[(b*3+h)*512 + o][m2]: u32x2 (8 B) per (b,o) at byte col lane*8
#pragma unroll
    for (int bb = 0; bb < 4; ++bb)
#pragma unroll
        for (int oo = 0; oo < 4; ++oo) {
            const size_t row = ((size_t)(b0 + bb) * 3 + h) * 512 + o0 + oo;
            u32x2 pk;
            pk.x = f2bf(aR[bb][oo][0]) | ((unsigned)f2bf(aI[bb][oo][0]) << 16);
            pk.y = f2bf(aR[bb][oo][1]) | ((unsigned)f2bf(aI[bb][oo][1]) << 16);
            *reinterpret_cast<u32x2*>(reinterpret_cast<char*>(Ybf) + row * 512 + lane * 8) = pk;
        }
}

extern "C" void kernel_launch(void* const* d_in, const int* in_sizes, int n_in,
                              void* d_out, int out_size, void* d_ws, size_t ws_size,
                              hipStream_t stream) {
    const float* q     = (const float*)d_in[0];
    const float* w_re  = (const float*)d_in[1];
    const float* w_im  = (const float*)d_in[2];
    const int*   index = (const int*)d_in[3];

    char* ws = (char*)d_ws;
    unsigned short* Xbf = (unsigned short*)(ws);                // 12,582,912 B
    unsigned short* Ybf = (unsigned short*)(ws + 25165824);     // 12,582,912 B
    unsigned short* T_A = (unsigned short*)(ws + 37748736);
    unsigned short* T_C = (unsigned short*)(ws + 39845888);

    build_ta<<<4096, 256, 0, stream>>>(index, T_A);
    build_tc<<<4096, 256, 0, stream>>>(index, T_C);
    gemm_a<<<384, 256, 0, stream>>>(q, T_A, Xbf);
    stage_b<<<768, 128, 0, stream>>>(Xbf, w_re, w_im, Ybf);
    gemm_bf16<1><<<6144, 256, 0, stream>>>(Ybf, T_C, (void*)d_out);
}

// Round 11
// 529.723 us; speedup vs baseline: 1.3626x; 1.2071x over previous
//
#include <hip/hip_runtime.h>
#include <hip/hip_bf16.h>

// FourierBlock: B=16, L=4096, H=3, E=512, M=128 modes.
// Pipeline:
//   1. build_ta: T_A[m2=256][l=4096] bf16
//   2. build_tc: T_C[l=4096][m2=256] bf16  (irfft scale folded in HERE ONLY)
//   3. gemm_a  : Xbf[h,b,i,m2] bf16 = q . T_A^T  (fused transpose+cast+MFMA)
//   4. stage_b : complex channel mix, v8: W staged via global_load_lds (read
//                ONCE from HBM), X per-thread from L2, K-split over i
//   5. reduce_y: Ybf += P1
//   6. gemm<1> : out = Ybf . T_C^T  (MFMA bf16, K=256)
//
// ws: Xbf bf16 12,582,912 B @0 | P1 @12582912 | Ybf @25165824
//     T_A 2 MB @37748736 | T_C 2 MB @39845888

#define L_TOT 4096

typedef __attribute__((ext_vector_type(4))) float f32x4;
typedef __attribute__((ext_vector_type(2))) float f32x2;
typedef __attribute__((ext_vector_type(2))) unsigned u32x2;
typedef __attribute__((ext_vector_type(8))) short s16x8;
typedef __attribute__((ext_vector_type(4))) unsigned short u16x4;

__device__ __forceinline__ unsigned short f2bf(float f) {
    unsigned u = __builtin_bit_cast(unsigned, f);
    u = (u + 0x7fffu + ((u >> 16) & 1u)) >> 16;
    return (unsigned short)u;
}

__device__ __forceinline__ void gload_lds16(const void* g, void* l) {
    __builtin_amdgcn_global_load_lds((const __attribute__((address_space(1))) void*)g,
                                     (__attribute__((address_space(3))) void*)l,
                                     16, 0, 0);
}

__global__ __launch_bounds__(256) void build_ta(const int* __restrict__ index,
                                                unsigned short* __restrict__ T_A) {
    const int idx = blockIdx.x * 256 + threadIdx.x;
    const int m2 = idx >> 12;
    const int l  = idx & (L_TOT - 1);
    const int k  = index[m2 >> 1];
    const int tt = (k * l) & (L_TOT - 1);
    const float x = (float)tt * (1.0f / 2048.0f);
    T_A[idx] = f2bf((m2 & 1) ? -sinpif(x) : cospif(x));
}

__global__ __launch_bounds__(256) void build_tc(const int* __restrict__ index,
                                                unsigned short* __restrict__ T_C) {
    const int idx = blockIdx.x * 256 + threadIdx.x;
    const int l  = idx >> 8;
    const int m2 = idx & 255;
    const int k  = index[m2 >> 1];
    const int tt = (k * l) & (L_TOT - 1);
    const float x = (float)tt * (1.0f / 2048.0f);
    const float s = (k == 0 ? 1.0f : 2.0f) * (1.0f / (float)L_TOT);
    T_C[idx] = f2bf(s * ((m2 & 1) ? -sinpif(x) : cospif(x)));
}

// ---- gemm_a: fused transpose+cast+GEMM (stage A of the DFT) ----
__global__ __launch_bounds__(256) void gemm_a(const float* __restrict__ q,
                                              const unsigned short* __restrict__ T_A,
                                              unsigned short* __restrict__ Xbf) {
    __shared__ unsigned short As[64 * 64];    // [ch][l^swz]  8 KB
    __shared__ unsigned short Bs[256 * 64];   // [m2][l^swz] 32 KB

    const int bid = blockIdx.x;
    const int b   = bid / 24;
    const int cht = bid % 24;
    const int ch0 = cht * 64;
    const int h   = ch0 >> 9;
    const int i0  = ch0 & 511;
    const int t   = threadIdx.x;
    const int lane = t & 63;
    const int w    = t >> 6;
    const int chq  = t & 15;
    const int lg   = t >> 4;

    const float* qb = q + (size_t)b * L_TOT * 1536 + ch0 + chq * 4;

    f32x4 acc[4][4];
#pragma unroll
    for (int mi = 0; mi < 4; ++mi)
#pragma unroll
        for (int ni = 0; ni < 4; ++ni) acc[mi][ni] = (f32x4)0.0f;

    for (int kt = 0; kt < L_TOT; kt += 64) {
        __syncthreads();
#pragma unroll
        for (int p = 0; p < 8; ++p) {
            const int u = p * 256 + t;
            const int row = u >> 3, c16 = u & 7;
            const unsigned short* src = T_A + (size_t)row * L_TOT + kt + ((c16 ^ (row & 7)) * 8);
            unsigned short* dst = Bs + (size_t)(p * 256 + w * 64) * 8;
            gload_lds16(src, dst);
        }
        f32x4 v[4];
#pragma unroll
        for (int r = 0; r < 4; ++r)
            v[r] = *reinterpret_cast<const f32x4*>(qb + (size_t)(kt + lg * 4 + r) * 1536);
#pragma unroll
        for (int j = 0; j < 4; ++j) {
            const int c = chq * 4 + j;
            uint2 pk;
            pk.x = f2bf(v[0][j]) | ((unsigned)f2bf(v[1][j]) << 16);
            pk.y = f2bf(v[2][j]) | ((unsigned)f2bf(v[3][j]) << 16);
            *reinterpret_cast<uint2*>(As + c * 64 + ((lg * 4) ^ ((c & 7) << 3))) = pk;
        }
        __syncthreads();

#pragma unroll
        for (int kk = 0; kk < 2; ++kk) {
            const int c16 = kk * 4 + (lane >> 4);
            s16x8 af[4], bfr[4];
#pragma unroll
            for (int mi = 0; mi < 4; ++mi) {
                const int row = mi * 16 + (lane & 15);
                af[mi] = *reinterpret_cast<const s16x8*>(As + row * 64 + ((c16 ^ (row & 7)) * 8));
            }
#pragma unroll
            for (int ni = 0; ni < 4; ++ni) {
                const int row = w * 64 + ni * 16 + (lane & 15);
                bfr[ni] = *reinterpret_cast<const s16x8*>(Bs + row * 64 + ((c16 ^ (row & 7)) * 8));
            }
#pragma unroll
            for (int mi = 0; mi < 4; ++mi)
#pragma unroll
                for (int ni = 0; ni < 4; ++ni)
                    acc[mi][ni] = __builtin_amdgcn_mfma_f32_16x16x32_bf16(af[mi], bfr[ni], acc[mi][ni], 0, 0, 0);
        }
    }

    const size_t cbase = (((size_t)h * 16 + b) * 512 + i0) * 256;
#pragma unroll
    for (int mi = 0; mi < 4; ++mi) {
        const int r0 = mi * 16 + (lane >> 4) * 4;
#pragma unroll
        for (int ni = 0; ni < 4; ++ni) {
            const int col = w * 64 + ni * 16 + (lane & 15);
#pragma unroll
            for (int j = 0; j < 4; ++j)
                Xbf[cbase + (size_t)(r0 + j) * 256 + col] = f2bf(acc[mi][ni][j]);
        }
    }
}

// ---- MFMA GEMM (stage C): out[(b,h,o)][l] f32 = Ybf . T_C^T ----
template <int MODE>
__global__ __launch_bounds__(256) void gemm_bf16(const unsigned short* __restrict__ A,
                                                 const unsigned short* __restrict__ Bt,
                                                 void* __restrict__ Cv) {
    constexpr int BM   = 128;
    constexpr int BK   = 64;
    constexpr int KTOT = 256;
    constexpr int LDAB = 256;
    constexpr int LDC  = 4096;
    constexpr int MFR  = BM / 32;
    constexpr int APASS = BM * 8 / 256;
    constexpr int BPASS = 4;

    __shared__ unsigned short As[BM * BK];
    __shared__ unsigned short Bs[128 * BK];

    const int t = threadIdx.x;
    const int lane = t & 63;
    const int w = t >> 6;
    const int wr = w >> 1, wc = w & 1;

    const int mt = blockIdx.x >> 5, nt = blockIdx.x & 31;
    const unsigned short* Ab = A + (size_t)mt * 128 * 256;
    const unsigned short* Bb = Bt + (size_t)nt * 128 * 256;
    const size_t cbase = (size_t)mt * 128 * 4096 + nt * 128;

    f32x4 acc[MFR][4];
#pragma unroll
    for (int mi = 0; mi < MFR; ++mi)
#pragma unroll
        for (int ni = 0; ni < 4; ++ni) acc[mi][ni] = (f32x4)0.0f;

    for (int kt = 0; kt < KTOT; kt += BK) {
        __syncthreads();
#pragma unroll
        for (int p = 0; p < APASS; ++p) {
            const int u = p * 256 + t;
            const int row = u >> 3, c16 = u & 7;
            const unsigned short* src = Ab + (size_t)row * LDAB + kt + ((c16 ^ (row & 7)) * 8);
            unsigned short* dst = As + (size_t)(p * 256 + w * 64) * 8;
            gload_lds16(src, dst);
        }
#pragma unroll
        for (int p = 0; p < BPASS; ++p) {
            const int u = p * 256 + t;
            const int row = u >> 3, c16 = u & 7;
            const unsigned short* src = Bb + (size_t)row * LDAB + kt + ((c16 ^ (row & 7)) * 8);
            unsigned short* dst = Bs + (size_t)(p * 256 + w * 64) * 8;
            gload_lds16(src, dst);
        }
        __syncthreads();

#pragma unroll
        for (int kk = 0; kk < 2; ++kk) {
            const int c16 = kk * 4 + (lane >> 4);
            s16x8 af[MFR], bfr[4];
#pragma unroll
            for (int mi = 0; mi < MFR; ++mi) {
                const int row = wr * (BM / 2) + mi * 16 + (lane & 15);
                af[mi] = *reinterpret_cast<const s16x8*>(As + row * BK + ((c16 ^ (row & 7)) * 8));
            }
#pragma unroll
            for (int ni = 0; ni < 4; ++ni) {
                const int row = wc * 64 + ni * 16 + (lane & 15);
                bfr[ni] = *reinterpret_cast<const s16x8*>(Bs + row * BK + ((c16 ^ (row & 7)) * 8));
            }
#pragma unroll
            for (int mi = 0; mi < MFR; ++mi)
#pragma unroll
                for (int ni = 0; ni < 4; ++ni)
                    acc[mi][ni] = __builtin_amdgcn_mfma_f32_16x16x32_bf16(af[mi], bfr[ni], acc[mi][ni], 0, 0, 0);
        }
    }

#pragma unroll
    for (int mi = 0; mi < MFR; ++mi) {
        const int r0 = wr * (BM / 2) + mi * 16 + (lane >> 4) * 4;
#pragma unroll
        for (int ni = 0; ni < 4; ++ni) {
            const int col = wc * 64 + ni * 16 + (lane & 15);
#pragma unroll
            for (int j = 0; j < 4; ++j)
                ((float*)Cv)[cbase + (size_t)(r0 + j) * LDC + col] = acc[mi][ni][j];
        }
    }
}

// ---- Stage B v8: W staged via global_load_lds (read ONCE), X from L2 ----
// grid 768: bid = ic*384 + h*128 + ot; block 256 = 4 waves.
// wave w: b-quad b0 = w*4; lane = m-pair (m = lane*2, lane*2+1); o-tile = 4.
// Per 8-i chunk: DMA W chunk [8i][4o][128m] (wr+wi = 32 KB) into LDS,
// then per i: 4 X u32x2 (L2) + 8 ds_read_b64 (conflict-free) + 128 FMA.
// W read exactly once from HBM (805 MB, the mandatory floor).
__global__ __launch_bounds__(256, 3) void stage_b(const unsigned short* __restrict__ Xbf,
                                                  const float* __restrict__ wr,
                                                  const float* __restrict__ wi,
                                                  unsigned short* __restrict__ Y0,
                                                  unsigned short* __restrict__ P1) {
    __shared__ float Wl[2][8][4][128];   // [ri][i][o][m] = 32 KB
    const int bid = blockIdx.x;
    const int ic  = bid / 384;
    const int g   = bid % 384;           // h*128 + ot
    const int h   = g >> 7;
    const int ot  = g & 127;
    const int t    = threadIdx.x;
    const int lane = t & 63;
    const int w    = t >> 6;
    const int b0   = w * 4;              // b0..b0+3
    const int o0   = ot * 4;             // o0..o0+3
    const int i_lo = ic * 256;

    const float* wr_base = wr + (size_t)h * 33554432 + (size_t)o0 * 128;
    const float* wi_base = wi + (size_t)h * 33554432 + (size_t)o0 * 128;
    // Xbf[h][b][i][m2]: +bb*131072, +i*256, lane*4 u16 (= 2 complex, 8 B)
    const unsigned short* x0 = Xbf + (size_t)(h * 16 + b0) * 512 * 256 + lane * 4;

    // per-thread staging indices: u = p*256 + t; row = u>>5 = i*4+o; col = u&31
    float aR[4][4][2], aI[4][4][2];      // [b][o][m]
#pragma unroll
    for (int bb = 0; bb < 4; ++bb)
#pragma unroll
        for (int oo = 0; oo < 4; ++oo) {
            aR[bb][oo][0] = aR[bb][oo][1] = 0.f;
            aI[bb][oo][0] = aI[bb][oo][1] = 0.f;
        }

#pragma unroll 1
    for (int c = 0; c < 32; ++c) {
        const int ib = i_lo + c * 8;
        __syncthreads();                 // protect Wl from previous readers
#pragma unroll
        for (int p = 0; p < 4; ++p) {
            const int u = p * 256 + t;
            const int row = u >> 5;      // i*4 + o
            const int col = u & 31;
            const int ii = row >> 2, oo = row & 3;
            const size_t goff = (size_t)(ib + ii) * 65536 + oo * 128 + col * 4;
            gload_lds16(wr_base + goff, (char*)&Wl[0][0][0][0] + (size_t)u * 16);
            gload_lds16(wi_base + goff, (char*)&Wl[1][0][0][0] + (size_t)u * 16);
        }
        __syncthreads();                 // vmcnt drain + visibility

#pragma unroll
        for (int i = 0; i < 8; ++i) {
            u32x2 xv[4];
#pragma unroll
            for (int bb = 0; bb < 4; ++bb)
                xv[bb] = *reinterpret_cast<const u32x2*>(x0 + (size_t)bb * 131072 + (size_t)(ib + i) * 256);
            f32x2 wrv[4], wiv[4];
#pragma unroll
            for (int oo = 0; oo < 4; ++oo) {
                wrv[oo] = *reinterpret_cast<const f32x2*>(&Wl[0][i][oo][lane * 2]);
                wiv[oo] = *reinterpret_cast<const f32x2*>(&Wl[1][i][oo][lane * 2]);
            }
#pragma unroll
            for (int bb = 0; bb < 4; ++bb) {
                float xr[2], xi[2];
#pragma unroll
                for (int mm = 0; mm < 2; ++mm) {
                    const unsigned xu = xv[bb][mm];
                    xr[mm] = __builtin_bit_cast(float, xu << 16);
                    xi[mm] = __builtin_bit_cast(float, xu & 0xffff0000u);
                }
#pragma unroll
                for (int oo = 0; oo < 4; ++oo)
#pragma unroll
                    for (int mm = 0; mm < 2; ++mm) {
                        const float wrj = wrv[oo][mm];
                        const float wij = wiv[oo][mm];
                        aR[bb][oo][mm] = fmaf(xr[mm], wrj, aR[bb][oo][mm]);
                        aR[bb][oo][mm] = fmaf(-xi[mm], wij, aR[bb][oo][mm]);
                        aI[bb][oo][mm] = fmaf(xr[mm], wij, aI[bb][oo][mm]);
                        aI[bb][oo][mm] = fmaf(xi[mm], wrj, aI[bb][oo][mm]);
                    }
            }
        }
    }

    unsigned short* yout = ic ? P1 : Y0;
#pragma unroll
    for (int bb = 0; bb < 4; ++bb)
#pragma unroll
        for (int oo = 0; oo < 4; ++oo) {
            const size_t row = ((size_t)(b0 + bb) * 3 + h) * 512 + o0 + oo;
            u32x2 pk;
            pk.x = f2bf(aR[bb][oo][0]) | ((unsigned)f2bf(aI[bb][oo][0]) << 16);
            pk.y = f2bf(aR[bb][oo][1]) | ((unsigned)f2bf(aI[bb][oo][1]) << 16);
            *reinterpret_cast<u32x2*>(reinterpret_cast<char*>(yout) + row * 512 + lane * 8) = pk;
        }
}

// ---- reduce_y: Ybf += P1 (bf16 pairs, f32 add) ----
__global__ __launch_bounds__(256) void reduce_y(unsigned short* __restrict__ Ybf,
                                                const unsigned short* __restrict__ P1) {
    const int idx = blockIdx.x * 256 + threadIdx.x;   // uint4 index, 786432 total
    const uint4 a = reinterpret_cast<const uint4*>(Ybf)[idx];
    const uint4 b = reinterpret_cast<const uint4*>(P1)[idx];
    const unsigned av[4] = {a.x, a.y, a.z, a.w};
    const unsigned bv[4] = {b.x, b.y, b.z, b.w};
    unsigned rv[4];
#pragma unroll
    for (int j = 0; j < 4; ++j) {
        const float xr = __builtin_bit_cast(float, av[j] << 16);
        const float xi = __builtin_bit_cast(float, av[j] & 0xffff0000u);
        const float yr = __builtin_bit_cast(float, bv[j] << 16);
        const float yi = __builtin_bit_cast(float, bv[j] & 0xffff0000u);
        rv[j] = f2bf(xr + yr) | ((unsigned)f2bf(xi + yi) << 16);
    }
    uint4 r;
    r.x = rv[0]; r.y = rv[1]; r.z = rv[2]; r.w = rv[3];
    reinterpret_cast<uint4*>(Ybf)[idx] = r;
}

extern "C" void kernel_launch(void* const* d_in, const int* in_sizes, int n_in,
                              void* d_out, int out_size, void* d_ws, size_t ws_size,
                              hipStream_t stream) {
    const float* q     = (const float*)d_in[0];
    const float* w_re  = (const float*)d_in[1];
    const float* w_im  = (const float*)d_in[2];
    const int*   index = (const int*)d_in[3];

    char* ws = (char*)d_ws;
    unsigned short* Xbf = (unsigned short*)(ws);                // 12,582,912 B
    unsigned short* P1  = (unsigned short*)(ws + 12582912);     // 12,582,912 B
    unsigned short* Ybf = (unsigned short*)(ws + 25165824);     // 12,582,912 B
    unsigned short* T_A = (unsigned short*)(ws + 37748736);
    unsigned short* T_C = (unsigned short*)(ws + 39845888);

    build_ta<<<4096, 256, 0, stream>>>(index, T_A);
    build_tc<<<4096, 256, 0, stream>>>(index, T_C);
    gemm_a<<<384, 256, 0, stream>>>(q, T_A, Xbf);
    stage_b<<<768, 256, 0, stream>>>(Xbf, w_re, w_im, Ybf, P1);
    reduce_y<<<3072, 256, 0, stream>>>(Ybf, P1);
    gemm_bf16<1><<<6144, 256, 0, stream>>>(Ybf, T_C, (void*)d_out);
}

// Round 12
// 476.562 us; speedup vs baseline: 1.5146x; 1.1116x over previous
//
#include <hip/hip_runtime.h>
#include <hip/hip_bf16.h>

// FourierBlock: B=16, L=4096, H=3, E=512, M=128 modes.
// Pipeline:
//   1. build_ta: T_A[m2=256][l=4096] bf16
//   2. build_tc: T_C[l=4096][m2=256] bf16  (irfft scale folded in HERE ONLY)
//   3. gemm_a  : Xbf[h,b,i,m2] bf16 = q . T_A^T  (fused transpose+cast+MFMA)
//   4. stage_b : complex channel mix, v9: W via global_load_lds with 2-phase
//                DOUBLE-BUFFER (stage next chunk before computing current),
//                X per-thread from L2, K-split over i
//   5. reduce_y: Ybf += P1
//   6. gemm<1> : out = Ybf . T_C^T  (MFMA bf16, K=256)
//
// ws: Xbf bf16 12,582,912 B @0 | P1 @12582912 | Ybf @25165824
//     T_A 2 MB @37748736 | T_C 2 MB @39845888

#define L_TOT 4096

typedef __attribute__((ext_vector_type(4))) float f32x4;
typedef __attribute__((ext_vector_type(2))) float f32x2;
typedef __attribute__((ext_vector_type(2))) unsigned u32x2;
typedef __attribute__((ext_vector_type(8))) short s16x8;
typedef __attribute__((ext_vector_type(4))) unsigned short u16x4;

__device__ __forceinline__ unsigned short f2bf(float f) {
    unsigned u = __builtin_bit_cast(unsigned, f);
    u = (u + 0x7fffu + ((u >> 16) & 1u)) >> 16;
    return (unsigned short)u;
}

__device__ __forceinline__ void gload_lds16(const void* g, void* l) {
    __builtin_amdgcn_global_load_lds((const __attribute__((address_space(1))) void*)g,
                                     (__attribute__((address_space(3))) void*)l,
                                     16, 0, 0);
}

__global__ __launch_bounds__(256) void build_ta(const int* __restrict__ index,
                                                unsigned short* __restrict__ T_A) {
    const int idx = blockIdx.x * 256 + threadIdx.x;
    const int m2 = idx >> 12;
    const int l  = idx & (L_TOT - 1);
    const int k  = index[m2 >> 1];
    const int tt = (k * l) & (L_TOT - 1);
    const float x = (float)tt * (1.0f / 2048.0f);
    T_A[idx] = f2bf((m2 & 1) ? -sinpif(x) : cospif(x));
}

__global__ __launch_bounds__(256) void build_tc(const int* __restrict__ index,
                                                unsigned short* __restrict__ T_C) {
    const int idx = blockIdx.x * 256 + threadIdx.x;
    const int l  = idx >> 8;
    const int m2 = idx & 255;
    const int k  = index[m2 >> 1];
    const int tt = (k * l) & (L_TOT - 1);
    const float x = (float)tt * (1.0f / 2048.0f);
    const float s = (k == 0 ? 1.0f : 2.0f) * (1.0f / (float)L_TOT);
    T_C[idx] = f2bf(s * ((m2 & 1) ? -sinpif(x) : cospif(x)));
}

// ---- gemm_a: fused transpose+cast+GEMM (stage A of the DFT) ----
__global__ __launch_bounds__(256) void gemm_a(const float* __restrict__ q,
                                              const unsigned short* __restrict__ T_A,
                                              unsigned short* __restrict__ Xbf) {
    __shared__ unsigned short As[64 * 64];    // [ch][l^swz]  8 KB
    __shared__ unsigned short Bs[256 * 64];   // [m2][l^swz] 32 KB

    const int bid = blockIdx.x;
    const int b   = bid / 24;
    const int cht = bid % 24;
    const int ch0 = cht * 64;
    const int h   = ch0 >> 9;
    const int i0  = ch0 & 511;
    const int t   = threadIdx.x;
    const int lane = t & 63;
    const int w    = t >> 6;
    const int chq  = t & 15;
    const int lg   = t >> 4;

    const float* qb = q + (size_t)b * L_TOT * 1536 + ch0 + chq * 4;

    f32x4 acc[4][4];
#pragma unroll
    for (int mi = 0; mi < 4; ++mi)
#pragma unroll
        for (int ni = 0; ni < 4; ++ni) acc[mi][ni] = (f32x4)0.0f;

    for (int kt = 0; kt < L_TOT; kt += 64) {
        __syncthreads();
#pragma unroll
        for (int p = 0; p < 8; ++p) {
            const int u = p * 256 + t;
            const int row = u >> 3, c16 = u & 7;
            const unsigned short* src = T_A + (size_t)row * L_TOT + kt + ((c16 ^ (row & 7)) * 8);
            unsigned short* dst = Bs + (size_t)(p * 256 + w * 64) * 8;
            gload_lds16(src, dst);
        }
        f32x4 v[4];
#pragma unroll
        for (int r = 0; r < 4; ++r)
            v[r] = *reinterpret_cast<const f32x4*>(qb + (size_t)(kt + lg * 4 + r) * 1536);
#pragma unroll
        for (int j = 0; j < 4; ++j) {
            const int c = chq * 4 + j;
            uint2 pk;
            pk.x = f2bf(v[0][j]) | ((unsigned)f2bf(v[1][j]) << 16);
            pk.y = f2bf(v[2][j]) | ((unsigned)f2bf(v[3][j]) << 16);
            *reinterpret_cast<uint2*>(As + c * 64 + ((lg * 4) ^ ((c & 7) << 3))) = pk;
        }
        __syncthreads();

#pragma unroll
        for (int kk = 0; kk < 2; ++kk) {
            const int c16 = kk * 4 + (lane >> 4);
            s16x8 af[4], bfr[4];
#pragma unroll
            for (int mi = 0; mi < 4; ++mi) {
                const int row = mi * 16 + (lane & 15);
                af[mi] = *reinterpret_cast<const s16x8*>(As + row * 64 + ((c16 ^ (row & 7)) * 8));
            }
#pragma unroll
            for (int ni = 0; ni < 4; ++ni) {
                const int row = w * 64 + ni * 16 + (lane & 15);
                bfr[ni] = *reinterpret_cast<const s16x8*>(Bs + row * 64 + ((c16 ^ (row & 7)) * 8));
            }
#pragma unroll
            for (int mi = 0; mi < 4; ++mi)
#pragma unroll
                for (int ni = 0; ni < 4; ++ni)
                    acc[mi][ni] = __builtin_amdgcn_mfma_f32_16x16x32_bf16(af[mi], bfr[ni], acc[mi][ni], 0, 0, 0);
        }
    }

    const size_t cbase = (((size_t)h * 16 + b) * 512 + i0) * 256;
#pragma unroll
    for (int mi = 0; mi < 4; ++mi) {
        const int r0 = mi * 16 + (lane >> 4) * 4;
#pragma unroll
        for (int ni = 0; ni < 4; ++ni) {
            const int col = w * 64 + ni * 16 + (lane & 15);
#pragma unroll
            for (int j = 0; j < 4; ++j)
                Xbf[cbase + (size_t)(r0 + j) * 256 + col] = f2bf(acc[mi][ni][j]);
        }
    }
}

// ---- MFMA GEMM (stage C): out[(b,h,o)][l] f32 = Ybf . T_C^T ----
template <int MODE>
__global__ __launch_bounds__(256) void gemm_bf16(const unsigned short* __restrict__ A,
                                                 const unsigned short* __restrict__ Bt,
                                                 void* __restrict__ Cv) {
    constexpr int BM   = 128;
    constexpr int BK   = 64;
    constexpr int KTOT = 256;
    constexpr int LDAB = 256;
    constexpr int LDC  = 4096;
    constexpr int MFR  = BM / 32;
    constexpr int APASS = BM * 8 / 256;
    constexpr int BPASS = 4;

    __shared__ unsigned short As[BM * BK];
    __shared__ unsigned short Bs[128 * BK];

    const int t = threadIdx.x;
    const int lane = t & 63;
    const int w = t >> 6;
    const int wr = w >> 1, wc = w & 1;

    const int mt = blockIdx.x >> 5, nt = blockIdx.x & 31;
    const unsigned short* Ab = A + (size_t)mt * 128 * 256;
    const unsigned short* Bb = Bt + (size_t)nt * 128 * 256;
    const size_t cbase = (size_t)mt * 128 * 4096 + nt * 128;

    f32x4 acc[MFR][4];
#pragma unroll
    for (int mi = 0; mi < MFR; ++mi)
#pragma unroll
        for (int ni = 0; ni < 4; ++ni) acc[mi][ni] = (f32x4)0.0f;

    for (int kt = 0; kt < KTOT; kt += BK) {
        __syncthreads();
#pragma unroll
        for (int p = 0; p < APASS; ++p) {
            const int u = p * 256 + t;
            const int row = u >> 3, c16 = u & 7;
            const unsigned short* src = Ab + (size_t)row * LDAB + kt + ((c16 ^ (row & 7)) * 8);
            unsigned short* dst = As + (size_t)(p * 256 + w * 64) * 8;
            gload_lds16(src, dst);
        }
#pragma unroll
        for (int p = 0; p < BPASS; ++p) {
            const int u = p * 256 + t;
            const int row = u >> 3, c16 = u & 7;
            const unsigned short* src = Bb + (size_t)row * LDAB + kt + ((c16 ^ (row & 7)) * 8);
            unsigned short* dst = Bs + (size_t)(p * 256 + w * 64) * 8;
            gload_lds16(src, dst);
        }
        __syncthreads();

#pragma unroll
        for (int kk = 0; kk < 2; ++kk) {
            const int c16 = kk * 4 + (lane >> 4);
            s16x8 af[MFR], bfr[4];
#pragma unroll
            for (int mi = 0; mi < MFR; ++mi) {
                const int row = wr * (BM / 2) + mi * 16 + (lane & 15);
                af[mi] = *reinterpret_cast<const s16x8*>(As + row * BK + ((c16 ^ (row & 7)) * 8));
            }
#pragma unroll
            for (int ni = 0; ni < 4; ++ni) {
                const int row = wc * 64 + ni * 16 + (lane & 15);
                bfr[ni] = *reinterpret_cast<const s16x8*>(Bs + row * BK + ((c16 ^ (row & 7)) * 8));
            }
#pragma unroll
            for (int mi = 0; mi < MFR; ++mi)
#pragma unroll
                for (int ni = 0; ni < 4; ++ni)
                    acc[mi][ni] = __builtin_amdgcn_mfma_f32_16x16x32_bf16(af[mi], bfr[ni], acc[mi][ni], 0, 0, 0);
        }
    }

#pragma unroll
    for (int mi = 0; mi < MFR; ++mi) {
        const int r0 = wr * (BM / 2) + mi * 16 + (lane >> 4) * 4;
#pragma unroll
        for (int ni = 0; ni < 4; ++ni) {
            const int col = wc * 64 + ni * 16 + (lane & 15);
#pragma unroll
            for (int j = 0; j < 4; ++j)
                ((float*)Cv)[cbase + (size_t)(r0 + j) * LDC + col] = acc[mi][ni][j];
        }
    }
}

// ---- Stage B v9: double-buffered W DMA (2-phase), X from L2, K-split ----
// grid 768: bid = ic*384 + h*128 + ot; block 256 = 4 waves.
// wave w: b-quad b0 = w*4; lane = m-pair; o-tile = 4.
// Chunk = 4 i: W chunk [4i][4o][128m] wr+wi = 16 KB; two buffers = 32 KB.
// Schedule per chunk c: STAGE(c+1 -> buf^1) FIRST, then compute buf from
// LDS + X(L2), then ONE barrier (vmcnt drain finds c+1's loads aged by the
// whole compute phase). W read exactly once from HBM.
#define SB_STAGE(BUF, IB)                                                      \
    _Pragma("unroll")                                                          \
    for (int p = 0; p < 2; ++p) {                                              \
        const int u = p * 256 + t;                                             \
        const int row = u >> 5;                                                \
        const int col = u & 31;                                                \
        const int ii = row >> 2, oo = row & 3;                                 \
        const size_t goff = (size_t)((IB) + ii) * 65536 + oo * 128 + col * 4;  \
        gload_lds16(wr_base + goff, (char*)&Wl[BUF][0][0][0][0] + (size_t)u * 16); \
        gload_lds16(wi_base + goff, (char*)&Wl[BUF][1][0][0][0] + (size_t)u * 16); \
    }

__global__ __launch_bounds__(256, 3) void stage_b(const unsigned short* __restrict__ Xbf,
                                                  const float* __restrict__ wr,
                                                  const float* __restrict__ wi,
                                                  unsigned short* __restrict__ Y0,
                                                  unsigned short* __restrict__ P1) {
    __shared__ float Wl[2][2][4][4][128];   // [buf][ri][i][o][m] = 32 KB
    const int bid = blockIdx.x;
    const int ic  = bid / 384;
    const int g   = bid % 384;           // h*128 + ot
    const int h   = g >> 7;
    const int ot  = g & 127;
    const int t    = threadIdx.x;
    const int lane = t & 63;
    const int w    = t >> 6;
    const int b0   = w * 4;              // b0..b0+3
    const int o0   = ot * 4;             // o0..o0+3
    const int i_lo = ic * 256;

    const float* wr_base = wr + (size_t)h * 33554432 + (size_t)o0 * 128;
    const float* wi_base = wi + (size_t)h * 33554432 + (size_t)o0 * 128;
    const unsigned short* x0 = Xbf + (size_t)(h * 16 + b0) * 512 * 256 + lane * 4;

    float aR[4][4][2], aI[4][4][2];      // [b][o][m]
#pragma unroll
    for (int bb = 0; bb < 4; ++bb)
#pragma unroll
        for (int oo = 0; oo < 4; ++oo) {
            aR[bb][oo][0] = aR[bb][oo][1] = 0.f;
            aI[bb][oo][0] = aI[bb][oo][1] = 0.f;
        }

    // prologue: stage chunk 0 into buf 0
    SB_STAGE(0, i_lo);
    __syncthreads();

    int cur = 0;
#pragma unroll 1
    for (int c = 0; c < 64; ++c) {
        const int ib = i_lo + c * 4;
        // issue next chunk's DMA into the other buffer BEFORE computing
        if (c + 1 < 64) {
            if (cur == 0) { SB_STAGE(1, ib + 4); }
            else          { SB_STAGE(0, ib + 4); }
        }
        // compute 4 i from Wl[cur]
#pragma unroll
        for (int i = 0; i < 4; ++i) {
            u32x2 xv[4];
#pragma unroll
            for (int bb = 0; bb < 4; ++bb)
                xv[bb] = *reinterpret_cast<const u32x2*>(x0 + (size_t)bb * 131072 + (size_t)(ib + i) * 256);
            f32x2 wrv[4], wiv[4];
#pragma unroll
            for (int oo = 0; oo < 4; ++oo) {
                wrv[oo] = *reinterpret_cast<const f32x2*>(&Wl[cur][0][i][oo][lane * 2]);
                wiv[oo] = *reinterpret_cast<const f32x2*>(&Wl[cur][1][i][oo][lane * 2]);
            }
#pragma unroll
            for (int bb = 0; bb < 4; ++bb) {
                float xr[2], xi[2];
#pragma unroll
                for (int mm = 0; mm < 2; ++mm) {
                    const unsigned xu = xv[bb][mm];
                    xr[mm] = __builtin_bit_cast(float, xu << 16);
                    xi[mm] = __builtin_bit_cast(float, xu & 0xffff0000u);
                }
#pragma unroll
                for (int oo = 0; oo < 4; ++oo)
#pragma unroll
                    for (int mm = 0; mm < 2; ++mm) {
                        const float wrj = wrv[oo][mm];
                        const float wij = wiv[oo][mm];
                        aR[bb][oo][mm] = fmaf(xr[mm], wrj, aR[bb][oo][mm]);
                        aR[bb][oo][mm] = fmaf(-xi[mm], wij, aR[bb][oo][mm]);
                        aI[bb][oo][mm] = fmaf(xr[mm], wij, aI[bb][oo][mm]);
                        aI[bb][oo][mm] = fmaf(xi[mm], wrj, aI[bb][oo][mm]);
                    }
            }
        }
        // one barrier per chunk: drains the (aged) DMA for c+1 and protects
        // buf[cur] from being overwritten while still being read
        __syncthreads();
        cur ^= 1;
    }

    unsigned short* yout = ic ? P1 : Y0;
#pragma unroll
    for (int bb = 0; bb < 4; ++bb)
#pragma unroll
        for (int oo = 0; oo < 4; ++oo) {
            const size_t row = ((size_t)(b0 + bb) * 3 + h) * 512 + o0 + oo;
            u32x2 pk;
            pk.x = f2bf(aR[bb][oo][0]) | ((unsigned)f2bf(aI[bb][oo][0]) << 16);
            pk.y = f2bf(aR[bb][oo][1]) | ((unsigned)f2bf(aI[bb][oo][1]) << 16);
            *reinterpret_cast<u32x2*>(reinterpret_cast<char*>(yout) + row * 512 + lane * 8) = pk;
        }
}

// ---- reduce_y: Ybf += P1 (bf16 pairs, f32 add) ----
__global__ __launch_bounds__(256) void reduce_y(unsigned short* __restrict__ Ybf,
                                                const unsigned short* __restrict__ P1) {
    const int idx = blockIdx.x * 256 + threadIdx.x;   // uint4 index, 786432 total
    const uint4 a = reinterpret_cast<const uint4*>(Ybf)[idx];
    const uint4 b = reinterpret_cast<const uint4*>(P1)[idx];
    const unsigned av[4] = {a.x, a.y, a.z, a.w};
    const unsigned bv[4] = {b.x, b.y, b.z, b.w};
    unsigned rv[4];
#pragma unroll
    for (int j = 0; j < 4; ++j) {
        const float xr = __builtin_bit_cast(float, av[j] << 16);
        const float xi = __builtin_bit_cast(float, av[j] & 0xffff0000u);
        const float yr = __builtin_bit_cast(float, bv[j] << 16);
        const float yi = __builtin_bit_cast(float, bv[j] & 0xffff0000u);
        rv[j] = f2bf(xr + yr) | ((unsigned)f2bf(xi + yi) << 16);
    }
    uint4 r;
    r.x = rv[0]; r.y = rv[1]; r.z = rv[2]; r.w = rv[3];
    reinterpret_cast<uint4*>(Ybf)[idx] = r;
}

extern "C" void kernel_launch(void* const* d_in, const int* in_sizes, int n_in,
                              void* d_out, int out_size, void* d_ws, size_t ws_size,
                              hipStream_t stream) {
    const float* q     = (const float*)d_in[0];
    const float* w_re  = (const float*)d_in[1];
    const float* w_im  = (const float*)d_in[2];
    const int*   index = (const int*)d_in[3];

    char* ws = (char*)d_ws;
    unsigned short* Xbf = (unsigned short*)(ws);                // 12,582,912 B
    unsigned short* P1  = (unsigned short*)(ws + 12582912);     // 12,582,912 B
    unsigned short* Ybf = (unsigned short*)(ws + 25165824);     // 12,582,912 B
    unsigned short* T_A = (unsigned short*)(ws + 37748736);
    unsigned short* T_C = (unsigned short*)(ws + 39845888);

    build_ta<<<4096, 256, 0, stream>>>(index, T_A);
    build_tc<<<4096, 256, 0, stream>>>(index, T_C);
    gemm_a<<<384, 256, 0, stream>>>(q, T_A, Xbf);
    stage_b<<<768, 256, 0, stream>>>(Xbf, w_re, w_im, Ybf, P1);
    reduce_y<<<3072, 256, 0, stream>>>(Ybf, P1);
    gemm_bf16<1><<<6144, 256, 0, stream>>>(Ybf, T_C, (void*)d_out);
}